// Round 13
// baseline (143.662 us; speedup 1.0000x reference)
//
#include <hip/hip_runtime.h>

#define NB    2048
#define AMAX  64
#define EDIM  128
#define TOTAL 66560          // = 520 * 128
#define DHEAD 16
#define KVSTR 20
#define XSTR  129
#define LSTR  136            // LDS row stride in fp16 (128 + 8 pad)
#define WELEM 65536          // winh (49152) + woh (16384) halfs
#define NSLOT 8192           // descriptor slots
#define UHALF (AMAX * LSTR)  // halfs per unit buffer (8704)

typedef _Float16 f16x8 __attribute__((ext_vector_type(8)));
typedef _Float16 f16x4 __attribute__((ext_vector_type(4)));
typedef float    f32x4 __attribute__((ext_vector_type(4)));

// ---------------- prep (r10-proven, unchanged) ----------------
// block 0: exclusive scan of ag -> offs; bucket samples by nt=ceil(n/16); pack tiles
//          into uniform 4-tile units (nt4 | nt3+nt1 | nt2+nt2 | leftovers) and emit
//          per-slot descriptors {row0, nrem, sid, base|n<<8}. General over any ag.
// blocks 1..64: convert win (49152 f32) and wout (16384 f32) to f16 wh[].
__global__ __launch_bounds__(256) void prep_kernel(const int* __restrict__ ag,
                                                   int* __restrict__ offs,
                                                   const float* __restrict__ win,
                                                   const float* __restrict__ wout,
                                                   _Float16* __restrict__ wh,
                                                   int4* __restrict__ dsc,
                                                   int* __restrict__ nblk) {
    if (blockIdx.x == 0) {
        __shared__ int part[256];
        __shared__ int cnt[8];
        __shared__ int rk[8];
        __shared__ int cb[8];
        const int t = threadIdx.x;
        int myn[8], loc[8];
        int s = 0;
#pragma unroll
        for (int i = 0; i < 8; ++i) { myn[i] = ag[t * 8 + i]; loc[i] = s; s += myn[i]; }
        part[t] = s;
        __syncthreads();
        for (int d = 1; d < 256; d <<= 1) {
            int v = (t >= d) ? part[t - d] : 0;
            __syncthreads();
            part[t] += v;
            __syncthreads();
        }
        const int base = (t == 0) ? 0 : part[t - 1];
#pragma unroll
        for (int i = 0; i < 8; ++i) offs[t * 8 + i] = base + loc[i];

        if (dsc != nullptr) {
            for (int j = t; j < NSLOT; j += 256)
                dsc[j] = make_int4(0, 0, -(j + 1), j & 3);
            if (t < 8) { cnt[t] = 0; rk[t] = 0; }
            __syncthreads();
#pragma unroll
            for (int i = 0; i < 8; ++i)
                atomicAdd(&cnt[(myn[i] + 15) >> 4], 1);
            __syncthreads();
            if (t == 0) {
                const int c4 = cnt[4], c3 = cnt[3], c2 = cnt[2], c1 = cnt[1];
                const int p31 = (c3 < c1) ? c3 : c1;
                const int q2 = c2 >> 1, odd2 = c2 & 1;
                int u1a = c1 - p31; const int cap = odd2 ? 2 : 0;
                if (u1a > cap) u1a = cap; if (u1a < 0) u1a = 0;
                const int rem1 = c1 - p31 - u1a;
                cb[4] = 0; cb[3] = c4; cb[2] = c4 + c3;
                cb[0] = p31; cb[1] = u1a;
                nblk[0] = c4 + c3 + q2 + odd2 + ((rem1 + 3) >> 2);
            }
            __syncthreads();
#pragma unroll
            for (int i = 0; i < 8; ++i) {
                const int sid = t * 8 + i, n = myn[i], off = base + loc[i];
                const int nt = (n + 15) >> 4;
                const int r = atomicAdd(&rk[nt], 1);
                int blk, s0;
                if (nt == 4)      { blk = r;            s0 = 0; }
                else if (nt == 3) { blk = cb[3] + r;    s0 = 0; }
                else if (nt == 2) { blk = cb[2] + (r >> 1); s0 = (r & 1) << 1; }
                else {
                    const int p31 = cb[0], u1a = cb[1], c2 = cnt[2];
                    if (r < p31)            { blk = cb[3] + r;          s0 = 3; }
                    else if (r < p31 + u1a) { blk = cb[2] + (c2 >> 1);  s0 = 2 + (r - p31); }
                    else {
                        const int rr = r - p31 - u1a;
                        blk = cb[2] + (c2 >> 1) + (c2 & 1) + (rr >> 2);
                        s0 = rr & 3;
                    }
                }
                for (int tt = 0; tt < nt; ++tt) {
                    int nrem = n - tt * 16; if (nrem > 16) nrem = 16;
                    dsc[blk * 4 + s0 + tt] = make_int4(off + tt * 16, nrem, sid, s0 | (n << 8));
                }
            }
        }
    } else {
        const int base = (blockIdx.x - 1) * 1024 + threadIdx.x * 4;
        const float4 v = (base < 49152) ? *(const float4*)(win + base)
                                        : *(const float4*)(wout + (base - 49152));
        f16x4 h;
        h[0] = (_Float16)v.x; h[1] = (_Float16)v.y;
        h[2] = (_Float16)v.z; h[3] = (_Float16)v.w;
        *(f16x4*)(wh + base) = h;
    }
}

// ---------------- fully fused, tile-packed, GLUED PAIRS (r10 body, 2 units/block) ----------------
// 512 threads / 8 waves per block; waves 0-3 process unit 2b (LDS buffer 0), waves 4-7
// process unit 2b+1 (LDS buffer 1). Per-wave code is bit-identical to the r10-verified
// kernel (wave-in-half index wid4 = wid&3; per-half xs buffer; ctx reuses xs after the
// barrier). Halves share the 3 block-wide barriers. Dummy descriptors make odd-NU
// tails benign (nrem=0 -> no stores; NaNs confined by MFMA row independence).
__global__ __launch_bounds__(512, 2) void fused_attn_kernel(
    const float*    __restrict__ x,     // [TOTAL][128] f32
    const _Float16* __restrict__ winh,  // [384][128] f16
    const float*    __restrict__ bin,   // [384] f32
    const _Float16* __restrict__ woh,   // [128][128] f16
    const float*    __restrict__ bout,  // [128] f32
    const int4*     __restrict__ dsc,
    const int*      __restrict__ nblk,
    float*          __restrict__ out)   // [TOTAL][128] f32
{
    __shared__ __align__(16) _Float16 xs[2 * UHALF];   // 34816 B: one buffer per half

    const int b = blockIdx.x;
    if (b * 2 >= nblk[0]) return;      // uniform: whole block exits together
    const int tid  = threadIdx.x;
    const int lane = tid & 63;
    const int wid  = __builtin_amdgcn_readfirstlane(tid >> 6);   // 0..7
    const int half = wid >> 2;                                   // unit select
    const int wid4 = wid & 3;                                    // role within unit
    const int l15  = lane & 15;
    const int quad = lane >> 4;
    const int u    = b * 2 + half;                               // this wave's unit

    _Float16* xsu = xs + half * UHALF;

    int4 dd[4];
#pragma unroll
    for (int t = 0; t < 4; ++t) dd[t] = dsc[u * 4 + t];

    // ---- weight fragments + biases FIRST: latency overlaps the x stage below ----
    f16x8 wq[2][4], wk[2][4], wv[2][4];
    float bqa[2][4], bka[2][4], bva[2];
#pragma unroll
    for (int m = 0; m < 2; ++m) {
        const int h = wid4 * 2 + m;
#pragma unroll
        for (int ks = 0; ks < 4; ++ks) {
            wq[m][ks] = *(const f16x8*)(winh + (size_t)(h * 16 + l15) * EDIM + ks * 32 + quad * 8);
            wk[m][ks] = *(const f16x8*)(winh + (size_t)(128 + h * 16 + l15) * EDIM + ks * 32 + quad * 8);
            wv[m][ks] = *(const f16x8*)(winh + (size_t)(256 + h * 16 + l15) * EDIM + ks * 32 + quad * 8);
        }
        const float4 bq = *(const float4*)(bin + h * 16 + quad * 4);
        const float4 bk = *(const float4*)(bin + 128 + h * 16 + quad * 4);
        bqa[m][0]=bq.x; bqa[m][1]=bq.y; bqa[m][2]=bq.z; bqa[m][3]=bq.w;
        bka[m][0]=bk.x; bka[m][1]=bk.y; bka[m][2]=bk.z; bka[m][3]=bk.w;
        bva[m] = bin[256 + h * 16 + l15];
    }

    // ---- stage x -> xsu (f16); threads 0-255 stage unit 2b, 256-511 stage unit 2b+1 ----
    {
        const int lt = tid & 255;                 // tid>>8 == half, so dd matches
        const int rr = lt >> 4, c8 = lt & 15;     // 16 rows x 16 chunks
#pragma unroll
        for (int t = 0; t < 4; ++t) {
            f16x8 hv = {};
            if (rr < dd[t].y) {
                const float* xr = x + (size_t)(dd[t].x + rr) * EDIM + c8 * 8;
                const float4 a0 = *(const float4*)xr;
                const float4 a1 = *(const float4*)(xr + 4);
                hv[0]=(_Float16)a0.x; hv[1]=(_Float16)a0.y; hv[2]=(_Float16)a0.z; hv[3]=(_Float16)a0.w;
                hv[4]=(_Float16)a1.x; hv[5]=(_Float16)a1.y; hv[6]=(_Float16)a1.z; hv[7]=(_Float16)a1.w;
            }
            *(f16x8*)(xsu + (t * 16 + rr) * LSTR + c8 * 8) = hv;
        }
    }
    __syncthreads();   // barrier 1: both units staged

    // ---- QKV projection: uniform over all 4 slots ----
    const float QSC = 0.25f * 1.44269504088896f;    // 1/sqrt(16) * log2(e)
    f16x4 qf[2][4], kf[2][4], vf[2][4];
#pragma unroll
    for (int kt = 0; kt < 4; ++kt) {
        f16x8 xf[4];
#pragma unroll
        for (int ks = 0; ks < 4; ++ks)
            xf[ks] = *(const f16x8*)(xsu + (kt * 16 + l15) * LSTR + ks * 32 + quad * 8);
#pragma unroll
        for (int m = 0; m < 2; ++m) {
            f32x4 aq = (f32x4){0.f,0.f,0.f,0.f};
            f32x4 ak = (f32x4){0.f,0.f,0.f,0.f};
            f32x4 av = (f32x4){0.f,0.f,0.f,0.f};
#pragma unroll
            for (int ks = 0; ks < 4; ++ks) {
                aq = __builtin_amdgcn_mfma_f32_16x16x32_f16(wq[m][ks], xf[ks], aq, 0, 0, 0);
                ak = __builtin_amdgcn_mfma_f32_16x16x32_f16(wk[m][ks], xf[ks], ak, 0, 0, 0);
                av = __builtin_amdgcn_mfma_f32_16x16x32_f16(xf[ks], wv[m][ks], av, 0, 0, 0);
            }
#pragma unroll
            for (int r = 0; r < 4; ++r) {
                qf[m][kt][r] = (_Float16)((aq[r] + bqa[m][r]) * QSC);
                kf[m][kt][r] = (_Float16)(ak[r] + bka[m][r]);
                vf[m][kt][r] = (_Float16)(av[r] + bva[m]);
            }
        }
    }

    // ---- attention: block-diagonal over slots; both heads interleaved ----
    f16x4 ctxf[2][4] = {};   // [head m][q-slot]; elem r -> qrow=quad*4+r (local), d=l15
#pragma unroll
    for (int qt = 0; qt < 4; ++qt) {
        const int baseq = dd[qt].w & 255;
        const int nsq   = dd[qt].w >> 8;
        const int sidq  = dd[qt].z;
        bool act[4];
#pragma unroll
        for (int kt = 0; kt < 4; ++kt) act[kt] = (dd[kt].z == sidq);

        f32x4 sv0[4], sv1[4];
#pragma unroll
        for (int kt = 0; kt < 4; ++kt) if (act[kt]) {
            sv0[kt] = __builtin_amdgcn_mfma_f32_16x16x16f16(
                          kf[0][kt], qf[0][qt], (f32x4){0.f,0.f,0.f,0.f}, 0, 0, 0);
            sv1[kt] = __builtin_amdgcn_mfma_f32_16x16x16f16(
                          kf[1][kt], qf[1][qt], (f32x4){0.f,0.f,0.f,0.f}, 0, 0, 0);
        }
        float t0[4], t1[4];
#pragma unroll
        for (int kt = 0; kt < 4; ++kt) { t0[kt] = 0.f; t1[kt] = 0.f; }
#pragma unroll
        for (int kt = 0; kt < 4; ++kt) if (act[kt]) {
            float s0 = 0.f, s1 = 0.f;
#pragma unroll
            for (int r = 0; r < 4; ++r) {
                const int key = (kt - baseq) * 16 + quad * 4 + r;
                const float p0 = (key < nsq) ? __builtin_amdgcn_exp2f(sv0[kt][r]) : 0.f;
                const float p1 = (key < nsq) ? __builtin_amdgcn_exp2f(sv1[kt][r]) : 0.f;
                s0 += p0; sv0[kt][r] = p0;
                s1 += p1; sv1[kt][r] = p1;
            }
            t0[kt] = s0; t1[kt] = s1;
        }
        float ls0 = (t0[0] + t0[1]) + (t0[2] + t0[3]);
        float ls1 = (t1[0] + t1[1]) + (t1[2] + t1[3]);
        ls0 += __shfl_xor(ls0, 16, 64);
        ls1 += __shfl_xor(ls1, 16, 64);
        ls0 += __shfl_xor(ls0, 32, 64);
        ls1 += __shfl_xor(ls1, 32, 64);
        const float inv0 = __builtin_amdgcn_rcpf(ls0);
        const float inv1 = __builtin_amdgcn_rcpf(ls1);
        f16x4 pf0[4], pf1[4];
#pragma unroll
        for (int kt = 0; kt < 4; ++kt) if (act[kt]) {
#pragma unroll
            for (int r = 0; r < 4; ++r) {
                pf0[kt][r] = (_Float16)(sv0[kt][r] * inv0);
                pf1[kt][r] = (_Float16)(sv1[kt][r] * inv1);
            }
        }
        f32x4 a0A = (f32x4){0.f,0.f,0.f,0.f}, a0B = (f32x4){0.f,0.f,0.f,0.f};
        f32x4 a1A = (f32x4){0.f,0.f,0.f,0.f}, a1B = (f32x4){0.f,0.f,0.f,0.f};
#pragma unroll
        for (int kt = 0; kt < 4; ++kt) if (act[kt]) {
            if ((kt & 1) == 0) {
                a0A = __builtin_amdgcn_mfma_f32_16x16x16f16(pf0[kt], vf[0][kt], a0A, 0, 0, 0);
                a1A = __builtin_amdgcn_mfma_f32_16x16x16f16(pf1[kt], vf[1][kt], a1A, 0, 0, 0);
            } else {
                a0B = __builtin_amdgcn_mfma_f32_16x16x16f16(pf0[kt], vf[0][kt], a0B, 0, 0, 0);
                a1B = __builtin_amdgcn_mfma_f32_16x16x16f16(pf1[kt], vf[1][kt], a1B, 0, 0, 0);
            }
        }
#pragma unroll
        for (int r = 0; r < 4; ++r) {
            ctxf[0][qt][r] = (_Float16)(a0A[r] + a0B[r]);
            ctxf[1][qt][r] = (_Float16)(a1A[r] + a1B[r]);
        }
    }

    // ---- ctx -> xsu (reuse; all proj reads of both halves fenced by this barrier) ----
    __syncthreads();   // barrier 2
#pragma unroll
    for (int m = 0; m < 2; ++m) {
        const int h = wid4 * 2 + m;
#pragma unroll
        for (int qt = 0; qt < 4; ++qt) {
#pragma unroll
            for (int r = 0; r < 4; ++r)
                xsu[(qt * 16 + quad * 4 + r) * LSTR + h * 16 + l15] = ctxf[m][qt][r];
        }
    }
    __syncthreads();   // barrier 3: ctx visible

    // ---- out-projection, column-split: wave w -> cols [32*wid4, +32), all 4 slots ----
    {
        f32x4 oacc[4][2];
#pragma unroll
        for (int t = 0; t < 4; ++t) { oacc[t][0] = (f32x4){0.f,0.f,0.f,0.f}; oacc[t][1] = (f32x4){0.f,0.f,0.f,0.f}; }
#pragma unroll
        for (int ks = 0; ks < 4; ++ks) {
            f16x8 cf[2];
#pragma unroll
            for (int c2 = 0; c2 < 2; ++c2)
                cf[c2] = *(const f16x8*)(woh + (wid4 * 32 + c2 * 16 + l15) * EDIM + ks * 32 + quad * 8);
#pragma unroll
            for (int t = 0; t < 4; ++t) {
                const f16x8 rf = *(const f16x8*)(xsu + (t * 16 + l15) * LSTR + ks * 32 + quad * 8);
                oacc[t][0] = __builtin_amdgcn_mfma_f32_16x16x32_f16(cf[0], rf, oacc[t][0], 0, 0, 0);
                oacc[t][1] = __builtin_amdgcn_mfma_f32_16x16x32_f16(cf[1], rf, oacc[t][1], 0, 0, 0);
            }
        }
        const float4 bo0 = *(const float4*)(bout + wid4 * 32 + quad * 4);
        const float4 bo1 = *(const float4*)(bout + wid4 * 32 + 16 + quad * 4);
#pragma unroll
        for (int t = 0; t < 4; ++t) {
            if (l15 < dd[t].y) {
                float* orow = out + (size_t)(dd[t].x + l15) * EDIM + wid4 * 32;
                *(float4*)(orow + quad * 4) =
                    make_float4(oacc[t][0][0] + bo0.x, oacc[t][0][1] + bo0.y,
                                oacc[t][0][2] + bo0.z, oacc[t][0][3] + bo0.w);
                *(float4*)(orow + 16 + quad * 4) =
                    make_float4(oacc[t][1][0] + bo1.x, oacc[t][1][1] + bo1.y,
                                oacc[t][1][2] + bo1.z, oacc[t][1][3] + bo1.w);
            }
        }
    }
}

// ================= fallback: fused fp32 kernel (used if ws too small) =================
__global__ __launch_bounds__(256, 2) void attn_fused_kernel(
    const float* __restrict__ x, const float* __restrict__ win,
    const float* __restrict__ bin, const float* __restrict__ wout,
    const float* __restrict__ bout, const int* __restrict__ ag,
    const int* __restrict__ offs, float* __restrict__ out)
{
    __shared__ __align__(16) float xs[AMAX * XSTR];
    __shared__ __align__(16) float kvs[8][AMAX * KVSTR];
    const int b = blockIdx.x, n = ag[b], off = offs[b];
    const int tid = threadIdx.x, lane = tid & 63;
    const int wid = __builtin_amdgcn_readfirstlane(tid >> 6);
#pragma unroll
    for (int it = 0; it < 8; ++it) {
        const int f4 = it * 256 + tid;
        const int r = f4 >> 5, c = (f4 & 31) << 2;
        float4 v = make_float4(0.f, 0.f, 0.f, 0.f);
        if (r < n) v = *(const float4*)(x + (size_t)(off + r) * EDIM + c);
        float* d = xs + r * XSTR + c;
        d[0]=v.x; d[1]=v.y; d[2]=v.z; d[3]=v.w;
    }
    __syncthreads();
    float* kw = kvs[wid*2+0]; float* vw = kvs[wid*2+1];
    const float* xrow = xs + lane * XSTR;
    float ctxk[2][DHEAD];
#pragma unroll
    for (int m = 0; m < 2; ++m) {
        const int h = wid * 2 + m;
        float qa[DHEAD], ka[DHEAD], va[DHEAD];
#pragma unroll
        for (int d = 0; d < DHEAD; ++d) { qa[d]=0.f; ka[d]=0.f; va[d]=0.f; }
        const float* wq = win + (size_t)(h*DHEAD)*EDIM;
        const float* wk = win + (size_t)(EDIM + h*DHEAD)*EDIM;
        const float* wv = win + (size_t)(2*EDIM + h*DHEAD)*EDIM;
        for (int k = 0; k < EDIM; ++k) {
            const float xv = xrow[k];
#pragma unroll
            for (int d = 0; d < DHEAD; ++d) {
                qa[d] = fmaf(xv, wq[d*EDIM+k], qa[d]);
                ka[d] = fmaf(xv, wk[d*EDIM+k], ka[d]);
                va[d] = fmaf(xv, wv[d*EDIM+k], va[d]);
            }
        }
#pragma unroll
        for (int d = 0; d < DHEAD; ++d) {
            qa[d] = (qa[d] + bin[h*DHEAD+d]) * 0.25f;
            ka[d] += bin[EDIM + h*DHEAD + d];
            va[d] += bin[2*EDIM + h*DHEAD + d];
        }
#pragma unroll
        for (int d = 0; d < DHEAD; ++d) { kw[lane*KVSTR+d] = ka[d]; vw[lane*KVSTR+d] = va[d]; }
        float mrun = -1e30f, lrun = 0.f, cacc[DHEAD];
#pragma unroll
        for (int d = 0; d < DHEAD; ++d) cacc[d] = 0.f;
        const int nch = (n + 15) >> 4;
        for (int ch = 0; ch < nch; ++ch) {
            const int jb = ch << 4;
            float s[16], p[16];
#pragma unroll
            for (int jj = 0; jj < 16; ++jj) {
                const float4* kr = (const float4*)(kw + (jb + jj) * KVSTR);
                const float4 k0=kr[0],k1=kr[1],k2=kr[2],k3=kr[3];
                const float kk[16] = {k0.x,k0.y,k0.z,k0.w,k1.x,k1.y,k1.z,k1.w,
                                      k2.x,k2.y,k2.z,k2.w,k3.x,k3.y,k3.z,k3.w};
                float a = 0.f;
#pragma unroll
                for (int d = 0; d < DHEAD; ++d) a = fmaf(qa[d], kk[d], a);
                s[jj] = (jb + jj < n) ? a : -1e30f;
            }
            float mc = s[0];
#pragma unroll
            for (int jj = 1; jj < 16; ++jj) mc = fmaxf(mc, s[jj]);
            const float mnew = fmaxf(mrun, mc);
            const float alpha = __expf(mrun - mnew);
            float psum = 0.f;
#pragma unroll
            for (int jj = 0; jj < 16; ++jj) { p[jj] = __expf(s[jj]-mnew); psum += p[jj]; }
            lrun = fmaf(lrun, alpha, psum);
#pragma unroll
            for (int d = 0; d < DHEAD; ++d) cacc[d] *= alpha;
#pragma unroll
            for (int jj = 0; jj < 16; ++jj) {
                const float4* vr = (const float4*)(vw + (jb + jj) * KVSTR);
                const float4 v0=vr[0],v1=vr[1],v2=vr[2],v3=vr[3];
                const float vv[16] = {v0.x,v0.y,v0.z,v0.w,v1.x,v1.y,v1.z,v1.w,
                                      v2.x,v2.y,v2.z,v2.w,v3.x,v3.y,v3.z,v3.w};
                const float pj = p[jj];
#pragma unroll
                for (int d = 0; d < DHEAD; ++d) cacc[d] = fmaf(pj, vv[d], cacc[d]);
            }
            mrun = mnew;
        }
        const float inv = 1.0f / lrun;
#pragma unroll
        for (int d = 0; d < DHEAD; ++d) ctxk[m][d] = cacc[d] * inv;
    }
    __syncthreads();
#pragma unroll
    for (int m = 0; m < 2; ++m) {
        const int h = wid * 2 + m;
#pragma unroll
        for (int d = 0; d < DHEAD; ++d) xs[lane*XSTR + h*DHEAD + d] = ctxk[m][d];
    }
    __syncthreads();
    const int c0 = wid * 32;
#pragma unroll
    for (int ct = 0; ct < 4; ++ct) {
        const int cc = c0 + ct * 8;
        float a8[8];
#pragma unroll
        for (int j = 0; j < 8; ++j) a8[j] = 0.f;
#pragma unroll 4
        for (int e = 0; e < EDIM; ++e) {
            const float cv = xrow[e];
#pragma unroll
            for (int j = 0; j < 8; ++j) a8[j] = fmaf(cv, wout[(size_t)(cc+j)*EDIM+e], a8[j]);
        }
        if (lane < n) {
            float* orow = out + (size_t)(off + lane) * EDIM + cc;
#pragma unroll
            for (int j = 0; j < 8; ++j) orow[j] = a8[j] + bout[cc+j];
        }
    }
}

extern "C" void kernel_launch(void* const* d_in, const int* in_sizes, int n_in,
                              void* d_out, int out_size, void* d_ws, size_t ws_size,
                              hipStream_t stream) {
    const float* x   = (const float*)d_in[0];
    const float* win = (const float*)d_in[1];
    const float* bin = (const float*)d_in[2];
    const float* wo  = (const float*)d_in[3];
    const float* bo  = (const float*)d_in[4];
    const int*   ag  = (const int*)d_in[5];
    float* out = (float*)d_out;

    // ws layout: wh [WELEM] f16 | dsc [NSLOT] int4 | offs [NB] int | nblk [4] int
    const size_t need = (size_t)WELEM * sizeof(_Float16) + (size_t)NSLOT * sizeof(int4)
                      + NB * sizeof(int) + 4 * sizeof(int);
    if (ws_size >= need) {
        _Float16* wh = (_Float16*)d_ws;
        int4* dsc = (int4*)(wh + WELEM);
        int* offs = (int*)(dsc + NSLOT);
        int* nblk = offs + NB;
        prep_kernel<<<65, 256, 0, stream>>>(ag, offs, win, wo, wh, dsc, nblk);
        fused_attn_kernel<<<NB / 2, 512, 0, stream>>>(x, wh, bin, wh + 49152, bo, dsc, nblk, out);
    } else {
        int* offs = (int*)d_ws;
        prep_kernel<<<1, 256, 0, stream>>>(ag, offs, nullptr, nullptr, nullptr, nullptr, nullptr);
        attn_fused_kernel<<<NB, 256, 0, stream>>>(x, win, bin, wo, bo, ag, offs, out);
    }
}

// Round 14
// 128.037 us; speedup vs baseline: 1.1220x; 1.1220x over previous
//
#include <hip/hip_runtime.h>

#define NB    2048
#define AMAX  64
#define EDIM  128
#define TOTAL 66560          // = 520 * 128
#define DHEAD 16
#define KVSTR 20
#define XSTR  129
#define LSTR  136            // LDS row stride in fp16 (128 + 8 pad)
#define WELEM 65536          // winh (49152) + woh (16384) halfs
#define NSLOT 8192           // 2048 blocks x 4 tile slots

typedef _Float16 f16x8 __attribute__((ext_vector_type(8)));
typedef _Float16 f16x4 __attribute__((ext_vector_type(4)));
typedef float    f32x4 __attribute__((ext_vector_type(4)));

// ---------------- prep ----------------
// block 0: exclusive scan of ag -> offs; bucket samples by nt=ceil(n/16); pack tiles
//          into uniform 4-tile blocks (nt4 | nt3+nt1 | nt2+nt2 | leftovers) and emit
//          per-slot descriptors {row0, nrem, sid, base|n<<8}. General over any ag.
// blocks 1..64: convert win (49152 f32) and wout (16384 f32) to f16 wh[].
__global__ __launch_bounds__(256) void prep_kernel(const int* __restrict__ ag,
                                                   int* __restrict__ offs,
                                                   const float* __restrict__ win,
                                                   const float* __restrict__ wout,
                                                   _Float16* __restrict__ wh,
                                                   int4* __restrict__ dsc,
                                                   int* __restrict__ nblk) {
    if (blockIdx.x == 0) {
        __shared__ int part[256];
        __shared__ int cnt[8];
        __shared__ int rk[8];
        __shared__ int cb[8];
        const int t = threadIdx.x;
        int myn[8], loc[8];
        int s = 0;
#pragma unroll
        for (int i = 0; i < 8; ++i) { myn[i] = ag[t * 8 + i]; loc[i] = s; s += myn[i]; }
        part[t] = s;
        __syncthreads();
        for (int d = 1; d < 256; d <<= 1) {
            int v = (t >= d) ? part[t - d] : 0;
            __syncthreads();
            part[t] += v;
            __syncthreads();
        }
        const int base = (t == 0) ? 0 : part[t - 1];
#pragma unroll
        for (int i = 0; i < 8; ++i) offs[t * 8 + i] = base + loc[i];

        if (dsc != nullptr) {
            // dummy descriptors everywhere first (unique sid, ns=0, base=own slot)
            for (int j = t; j < NSLOT; j += 256)
                dsc[j] = make_int4(0, 0, -(j + 1), j & 3);
            if (t < 8) { cnt[t] = 0; rk[t] = 0; }
            __syncthreads();
#pragma unroll
            for (int i = 0; i < 8; ++i)
                atomicAdd(&cnt[(myn[i] + 15) >> 4], 1);
            __syncthreads();
            if (t == 0) {
                const int c4 = cnt[4], c3 = cnt[3], c2 = cnt[2], c1 = cnt[1];
                const int p31 = (c3 < c1) ? c3 : c1;
                const int q2 = c2 >> 1, odd2 = c2 & 1;
                int u1a = c1 - p31; const int cap = odd2 ? 2 : 0;
                if (u1a > cap) u1a = cap; if (u1a < 0) u1a = 0;
                const int rem1 = c1 - p31 - u1a;
                cb[4] = 0; cb[3] = c4; cb[2] = c4 + c3;
                cb[0] = p31; cb[1] = u1a;
                nblk[0] = c4 + c3 + q2 + odd2 + ((rem1 + 3) >> 2);
            }
            __syncthreads();
#pragma unroll
            for (int i = 0; i < 8; ++i) {
                const int sid = t * 8 + i, n = myn[i], off = base + loc[i];
                const int nt = (n + 15) >> 4;
                const int r = atomicAdd(&rk[nt], 1);
                int blk, s0;
                if (nt == 4)      { blk = r;            s0 = 0; }
                else if (nt == 3) { blk = cb[3] + r;    s0 = 0; }
                else if (nt == 2) { blk = cb[2] + (r >> 1); s0 = (r & 1) << 1; }
                else {
                    const int p31 = cb[0], u1a = cb[1], c2 = cnt[2];
                    if (r < p31)            { blk = cb[3] + r;          s0 = 3; }
                    else if (r < p31 + u1a) { blk = cb[2] + (c2 >> 1);  s0 = 2 + (r - p31); }
                    else {
                        const int rr = r - p31 - u1a;
                        blk = cb[2] + (c2 >> 1) + (c2 & 1) + (rr >> 2);
                        s0 = rr & 3;
                    }
                }
                for (int tt = 0; tt < nt; ++tt) {
                    int nrem = n - tt * 16; if (nrem > 16) nrem = 16;
                    dsc[blk * 4 + s0 + tt] = make_int4(off + tt * 16, nrem, sid, s0 | (n << 8));
                }
            }
        }
    } else {
        // blocks 1..48 -> win, 49..64 -> wout (1024-elem chunks never straddle)
        const int base = (blockIdx.x - 1) * 1024 + threadIdx.x * 4;
        const float4 v = (base < 49152) ? *(const float4*)(win + base)
                                        : *(const float4*)(wout + (base - 49152));
        f16x4 h;
        h[0] = (_Float16)v.x; h[1] = (_Float16)v.y;
        h[2] = (_Float16)v.z; h[3] = (_Float16)v.w;
        *(f16x4*)(wh + base) = h;
    }
}

// ---------------- fully fused, tile-packed (r10-verified optimum) ----------------
// Uniform 4-tile blocks (descriptors from prep). 4 waves; wave w owns heads {2w,2w+1}
// interleaved. Per slot t: {row0, nrem, sid, base|ns<<8}. Attention is block-diagonal
// over slots: q-slot qt attends k-slots with equal sid; key index (kt-base)*16+... < ns.
// Garbage rows of padded/dummy slots are confined by MFMA row-independence, never stored.
__global__ __launch_bounds__(256, 2) void fused_attn_kernel(
    const float*    __restrict__ x,     // [TOTAL][128] f32
    const _Float16* __restrict__ winh,  // [384][128] f16
    const float*    __restrict__ bin,   // [384] f32
    const _Float16* __restrict__ woh,   // [128][128] f16
    const float*    __restrict__ bout,  // [128] f32
    const int4*     __restrict__ dsc,
    const int*      __restrict__ nblk,
    float*          __restrict__ out)   // [TOTAL][128] f32
{
    __shared__ __align__(16) _Float16 xs[AMAX * LSTR];   // 17408 B; x tile, then ctx

    const int b = blockIdx.x;
    if (b >= nblk[0]) return;
    const int tid  = threadIdx.x;
    const int lane = tid & 63;
    const int wid  = __builtin_amdgcn_readfirstlane(tid >> 6);
    const int l15  = lane & 15;
    const int quad = lane >> 4;

    int4 dd[4];
#pragma unroll
    for (int t = 0; t < 4; ++t) dd[t] = dsc[b * 4 + t];

    // ---- weight fragments + biases FIRST: latency overlaps the x stage below ----
    f16x8 wq[2][4], wk[2][4], wv[2][4];
    float bqa[2][4], bka[2][4], bva[2];
#pragma unroll
    for (int m = 0; m < 2; ++m) {
        const int h = wid * 2 + m;
#pragma unroll
        for (int ks = 0; ks < 4; ++ks) {
            wq[m][ks] = *(const f16x8*)(winh + (size_t)(h * 16 + l15) * EDIM + ks * 32 + quad * 8);
            wk[m][ks] = *(const f16x8*)(winh + (size_t)(128 + h * 16 + l15) * EDIM + ks * 32 + quad * 8);
            wv[m][ks] = *(const f16x8*)(winh + (size_t)(256 + h * 16 + l15) * EDIM + ks * 32 + quad * 8);
        }
        const float4 bq = *(const float4*)(bin + h * 16 + quad * 4);
        const float4 bk = *(const float4*)(bin + 128 + h * 16 + quad * 4);
        bqa[m][0]=bq.x; bqa[m][1]=bq.y; bqa[m][2]=bq.z; bqa[m][3]=bq.w;
        bka[m][0]=bk.x; bka[m][1]=bk.y; bka[m][2]=bk.z; bka[m][3]=bk.w;
        bva[m] = bin[256 + h * 16 + l15];
    }

    // ---- stage x -> xs (f16) per slot; rows >= nrem zero-filled ----
    {
        const int rr = tid >> 4, c8 = tid & 15;   // 16 rows x 16 chunks = 256 threads
#pragma unroll
        for (int t = 0; t < 4; ++t) {
            f16x8 hv = {};
            if (rr < dd[t].y) {
                const float* xr = x + (size_t)(dd[t].x + rr) * EDIM + c8 * 8;
                const float4 a0 = *(const float4*)xr;
                const float4 a1 = *(const float4*)(xr + 4);
                hv[0]=(_Float16)a0.x; hv[1]=(_Float16)a0.y; hv[2]=(_Float16)a0.z; hv[3]=(_Float16)a0.w;
                hv[4]=(_Float16)a1.x; hv[5]=(_Float16)a1.y; hv[6]=(_Float16)a1.z; hv[7]=(_Float16)a1.w;
            }
            *(f16x8*)(xs + (t * 16 + rr) * LSTR + c8 * 8) = hv;
        }
    }
    __syncthreads();

    // ---- QKV projection: uniform over all 4 slots ----
    const float QSC = 0.25f * 1.44269504088896f;    // fold 1/sqrt(16) * log2(e)
    f16x4 qf[2][4], kf[2][4], vf[2][4];
#pragma unroll
    for (int kt = 0; kt < 4; ++kt) {
        f16x8 xf[4];
#pragma unroll
        for (int ks = 0; ks < 4; ++ks)
            xf[ks] = *(const f16x8*)(xs + (kt * 16 + l15) * LSTR + ks * 32 + quad * 8);
#pragma unroll
        for (int m = 0; m < 2; ++m) {
            f32x4 aq = (f32x4){0.f,0.f,0.f,0.f};
            f32x4 ak = (f32x4){0.f,0.f,0.f,0.f};
            f32x4 av = (f32x4){0.f,0.f,0.f,0.f};
#pragma unroll
            for (int ks = 0; ks < 4; ++ks) {
                aq = __builtin_amdgcn_mfma_f32_16x16x32_f16(wq[m][ks], xf[ks], aq, 0, 0, 0);
                ak = __builtin_amdgcn_mfma_f32_16x16x32_f16(wk[m][ks], xf[ks], ak, 0, 0, 0);
                av = __builtin_amdgcn_mfma_f32_16x16x32_f16(xf[ks], wv[m][ks], av, 0, 0, 0);
            }
#pragma unroll
            for (int r = 0; r < 4; ++r) {
                qf[m][kt][r] = (_Float16)((aq[r] + bqa[m][r]) * QSC);
                kf[m][kt][r] = (_Float16)(ak[r] + bka[m][r]);
                vf[m][kt][r] = (_Float16)(av[r] + bva[m]);
            }
        }
    }

    // ---- attention: block-diagonal over slots; both heads interleaved ----
    f16x4 ctxf[2][4] = {};   // [head m][q-slot]; elem r -> qrow=quad*4+r (local), d=l15
#pragma unroll
    for (int qt = 0; qt < 4; ++qt) {
        const int baseq = dd[qt].w & 255;
        const int nsq   = dd[qt].w >> 8;
        const int sidq  = dd[qt].z;
        bool act[4];
#pragma unroll
        for (int kt = 0; kt < 4; ++kt) act[kt] = (dd[kt].z == sidq);

        f32x4 sv0[4], sv1[4];
#pragma unroll
        for (int kt = 0; kt < 4; ++kt) if (act[kt]) {
            sv0[kt] = __builtin_amdgcn_mfma_f32_16x16x16f16(
                          kf[0][kt], qf[0][qt], (f32x4){0.f,0.f,0.f,0.f}, 0, 0, 0);
            sv1[kt] = __builtin_amdgcn_mfma_f32_16x16x16f16(
                          kf[1][kt], qf[1][qt], (f32x4){0.f,0.f,0.f,0.f}, 0, 0, 0);
        }
        float t0[4], t1[4];
#pragma unroll
        for (int kt = 0; kt < 4; ++kt) { t0[kt] = 0.f; t1[kt] = 0.f; }
#pragma unroll
        for (int kt = 0; kt < 4; ++kt) if (act[kt]) {
            float s0 = 0.f, s1 = 0.f;
#pragma unroll
            for (int r = 0; r < 4; ++r) {
                const int key = (kt - baseq) * 16 + quad * 4 + r;
                const float p0 = (key < nsq) ? __builtin_amdgcn_exp2f(sv0[kt][r]) : 0.f;
                const float p1 = (key < nsq) ? __builtin_amdgcn_exp2f(sv1[kt][r]) : 0.f;
                s0 += p0; sv0[kt][r] = p0;
                s1 += p1; sv1[kt][r] = p1;
            }
            t0[kt] = s0; t1[kt] = s1;
        }
        float ls0 = (t0[0] + t0[1]) + (t0[2] + t0[3]);
        float ls1 = (t1[0] + t1[1]) + (t1[2] + t1[3]);
        ls0 += __shfl_xor(ls0, 16, 64);
        ls1 += __shfl_xor(ls1, 16, 64);
        ls0 += __shfl_xor(ls0, 32, 64);
        ls1 += __shfl_xor(ls1, 32, 64);
        const float inv0 = __builtin_amdgcn_rcpf(ls0);
        const float inv1 = __builtin_amdgcn_rcpf(ls1);
        f16x4 pf0[4], pf1[4];
#pragma unroll
        for (int kt = 0; kt < 4; ++kt) if (act[kt]) {
#pragma unroll
            for (int r = 0; r < 4; ++r) {
                pf0[kt][r] = (_Float16)(sv0[kt][r] * inv0);
                pf1[kt][r] = (_Float16)(sv1[kt][r] * inv1);
            }
        }
        f32x4 a0A = (f32x4){0.f,0.f,0.f,0.f}, a0B = (f32x4){0.f,0.f,0.f,0.f};
        f32x4 a1A = (f32x4){0.f,0.f,0.f,0.f}, a1B = (f32x4){0.f,0.f,0.f,0.f};
#pragma unroll
        for (int kt = 0; kt < 4; ++kt) if (act[kt]) {
            if ((kt & 1) == 0) {
                a0A = __builtin_amdgcn_mfma_f32_16x16x16f16(pf0[kt], vf[0][kt], a0A, 0, 0, 0);
                a1A = __builtin_amdgcn_mfma_f32_16x16x16f16(pf1[kt], vf[1][kt], a1A, 0, 0, 0);
            } else {
                a0B = __builtin_amdgcn_mfma_f32_16x16x16f16(pf0[kt], vf[0][kt], a0B, 0, 0, 0);
                a1B = __builtin_amdgcn_mfma_f32_16x16x16f16(pf1[kt], vf[1][kt], a1B, 0, 0, 0);
            }
        }
#pragma unroll
        for (int r = 0; r < 4; ++r) {
            ctxf[0][qt][r] = (_Float16)(a0A[r] + a0B[r]);
            ctxf[1][qt][r] = (_Float16)(a1A[r] + a1B[r]);
        }
    }

    // ---- ctx -> LDS (reuse xs; all xs reads done before this barrier) ----
    __syncthreads();
#pragma unroll
    for (int m = 0; m < 2; ++m) {
        const int h = wid * 2 + m;
#pragma unroll
        for (int qt = 0; qt < 4; ++qt) {
#pragma unroll
            for (int r = 0; r < 4; ++r)
                xs[(qt * 16 + quad * 4 + r) * LSTR + h * 16 + l15] = ctxf[m][qt][r];
        }
    }
    __syncthreads();

    // ---- out-projection, column-split: wave w -> cols [32w,32w+32), all 4 slots ----
    {
        f32x4 oacc[4][2];
#pragma unroll
        for (int t = 0; t < 4; ++t) { oacc[t][0] = (f32x4){0.f,0.f,0.f,0.f}; oacc[t][1] = (f32x4){0.f,0.f,0.f,0.f}; }
#pragma unroll
        for (int ks = 0; ks < 4; ++ks) {
            f16x8 cf[2];
#pragma unroll
            for (int c2 = 0; c2 < 2; ++c2)
                cf[c2] = *(const f16x8*)(woh + (wid * 32 + c2 * 16 + l15) * EDIM + ks * 32 + quad * 8);
#pragma unroll
            for (int t = 0; t < 4; ++t) {
                const f16x8 rf = *(const f16x8*)(xs + (t * 16 + l15) * LSTR + ks * 32 + quad * 8);
                oacc[t][0] = __builtin_amdgcn_mfma_f32_16x16x32_f16(cf[0], rf, oacc[t][0], 0, 0, 0);
                oacc[t][1] = __builtin_amdgcn_mfma_f32_16x16x32_f16(cf[1], rf, oacc[t][1], 0, 0, 0);
            }
        }
        const float4 bo0 = *(const float4*)(bout + wid * 32 + quad * 4);
        const float4 bo1 = *(const float4*)(bout + wid * 32 + 16 + quad * 4);
#pragma unroll
        for (int t = 0; t < 4; ++t) {
            if (l15 < dd[t].y) {
                float* orow = out + (size_t)(dd[t].x + l15) * EDIM + wid * 32;
                *(float4*)(orow + quad * 4) =
                    make_float4(oacc[t][0][0] + bo0.x, oacc[t][0][1] + bo0.y,
                                oacc[t][0][2] + bo0.z, oacc[t][0][3] + bo0.w);
                *(float4*)(orow + 16 + quad * 4) =
                    make_float4(oacc[t][1][0] + bo1.x, oacc[t][1][1] + bo1.y,
                                oacc[t][1][2] + bo1.z, oacc[t][1][3] + bo1.w);
            }
        }
    }
}

// ================= fallback: fused fp32 kernel (used if ws too small) =================
__global__ __launch_bounds__(256, 2) void attn_fused_kernel(
    const float* __restrict__ x, const float* __restrict__ win,
    const float* __restrict__ bin, const float* __restrict__ wout,
    const float* __restrict__ bout, const int* __restrict__ ag,
    const int* __restrict__ offs, float* __restrict__ out)
{
    __shared__ __align__(16) float xs[AMAX * XSTR];
    __shared__ __align__(16) float kvs[8][AMAX * KVSTR];
    const int b = blockIdx.x, n = ag[b], off = offs[b];
    const int tid = threadIdx.x, lane = tid & 63;
    const int wid = __builtin_amdgcn_readfirstlane(tid >> 6);
#pragma unroll
    for (int it = 0; it < 8; ++it) {
        const int f4 = it * 256 + tid;
        const int r = f4 >> 5, c = (f4 & 31) << 2;
        float4 v = make_float4(0.f, 0.f, 0.f, 0.f);
        if (r < n) v = *(const float4*)(x + (size_t)(off + r) * EDIM + c);
        float* d = xs + r * XSTR + c;
        d[0]=v.x; d[1]=v.y; d[2]=v.z; d[3]=v.w;
    }
    __syncthreads();
    float* kw = kvs[wid*2+0]; float* vw = kvs[wid*2+1];
    const float* xrow = xs + lane * XSTR;
    float ctxk[2][DHEAD];
#pragma unroll
    for (int m = 0; m < 2; ++m) {
        const int h = wid * 2 + m;
        float qa[DHEAD], ka[DHEAD], va[DHEAD];
#pragma unroll
        for (int d = 0; d < DHEAD; ++d) { qa[d]=0.f; ka[d]=0.f; va[d]=0.f; }
        const float* wq = win + (size_t)(h*DHEAD)*EDIM;
        const float* wk = win + (size_t)(EDIM + h*DHEAD)*EDIM;
        const float* wv = win + (size_t)(2*EDIM + h*DHEAD)*EDIM;
        for (int k = 0; k < EDIM; ++k) {
            const float xv = xrow[k];
#pragma unroll
            for (int d = 0; d < DHEAD; ++d) {
                qa[d] = fmaf(xv, wq[d*EDIM+k], qa[d]);
                ka[d] = fmaf(xv, wk[d*EDIM+k], ka[d]);
                va[d] = fmaf(xv, wv[d*EDIM+k], va[d]);
            }
        }
#pragma unroll
        for (int d = 0; d < DHEAD; ++d) {
            qa[d] = (qa[d] + bin[h*DHEAD+d]) * 0.25f;
            ka[d] += bin[EDIM + h*DHEAD + d];
            va[d] += bin[2*EDIM + h*DHEAD + d];
        }
#pragma unroll
        for (int d = 0; d < DHEAD; ++d) { kw[lane*KVSTR+d] = ka[d]; vw[lane*KVSTR+d] = va[d]; }
        float mrun = -1e30f, lrun = 0.f, cacc[DHEAD];
#pragma unroll
        for (int d = 0; d < DHEAD; ++d) cacc[d] = 0.f;
        const int nch = (n + 15) >> 4;
        for (int ch = 0; ch < nch; ++ch) {
            const int jb = ch << 4;
            float s[16], p[16];
#pragma unroll
            for (int jj = 0; jj < 16; ++jj) {
                const float4* kr = (const float4*)(kw + (jb + jj) * KVSTR);
                const float4 k0=kr[0],k1=kr[1],k2=kr[2],k3=kr[3];
                const float kk[16] = {k0.x,k0.y,k0.z,k0.w,k1.x,k1.y,k1.z,k1.w,
                                      k2.x,k2.y,k2.z,k2.w,k3.x,k3.y,k3.z,k3.w};
                float a = 0.f;
#pragma unroll
                for (int d = 0; d < DHEAD; ++d) a = fmaf(qa[d], kk[d], a);
                s[jj] = (jb + jj < n) ? a : -1e30f;
            }
            float mc = s[0];
#pragma unroll
            for (int jj = 1; jj < 16; ++jj) mc = fmaxf(mc, s[jj]);
            const float mnew = fmaxf(mrun, mc);
            const float alpha = __expf(mrun - mnew);
            float psum = 0.f;
#pragma unroll
            for (int jj = 0; jj < 16; ++jj) { p[jj] = __expf(s[jj]-mnew); psum += p[jj]; }
            lrun = fmaf(lrun, alpha, psum);
#pragma unroll
            for (int d = 0; d < DHEAD; ++d) cacc[d] *= alpha;
#pragma unroll
            for (int jj = 0; jj < 16; ++jj) {
                const float4* vr = (const float4*)(vw + (jb + jj) * KVSTR);
                const float4 v0=vr[0],v1=vr[1],v2=vr[2],v3=vr[3];
                const float vv[16] = {v0.x,v0.y,v0.z,v0.w,v1.x,v1.y,v1.z,v1.w,
                                      v2.x,v2.y,v2.z,v2.w,v3.x,v3.y,v3.z,v3.w};
                const float pj = p[jj];
#pragma unroll
                for (int d = 0; d < DHEAD; ++d) cacc[d] = fmaf(pj, vv[d], cacc[d]);
            }
            mrun = mnew;
        }
        const float inv = 1.0f / lrun;
#pragma unroll
        for (int d = 0; d < DHEAD; ++d) ctxk[m][d] = cacc[d] * inv;
    }
    __syncthreads();
#pragma unroll
    for (int m = 0; m < 2; ++m) {
        const int h = wid * 2 + m;
#pragma unroll
        for (int d = 0; d < DHEAD; ++d) xs[lane*XSTR + h*DHEAD + d] = ctxk[m][d];
    }
    __syncthreads();
    const int c0 = wid * 32;
#pragma unroll
    for (int ct = 0; ct < 4; ++ct) {
        const int cc = c0 + ct * 8;
        float a8[8];
#pragma unroll
        for (int j = 0; j < 8; ++j) a8[j] = 0.f;
#pragma unroll 4
        for (int e = 0; e < EDIM; ++e) {
            const float cv = xrow[e];
#pragma unroll
            for (int j = 0; j < 8; ++j) a8[j] = fmaf(cv, wout[(size_t)(cc+j)*EDIM+e], a8[j]);
        }
        if (lane < n) {
            float* orow = out + (size_t)(off + lane) * EDIM + cc;
#pragma unroll
            for (int j = 0; j < 8; ++j) orow[j] = a8[j] + bout[cc+j];
        }
    }
}

extern "C" void kernel_launch(void* const* d_in, const int* in_sizes, int n_in,
                              void* d_out, int out_size, void* d_ws, size_t ws_size,
                              hipStream_t stream) {
    const float* x   = (const float*)d_in[0];
    const float* win = (const float*)d_in[1];
    const float* bin = (const float*)d_in[2];
    const float* wo  = (const float*)d_in[3];
    const float* bo  = (const float*)d_in[4];
    const int*   ag  = (const int*)d_in[5];
    float* out = (float*)d_out;

    // ws layout: wh [WELEM] f16 | dsc [NSLOT] int4 | offs [NB] int | nblk [4] int
    const size_t need = (size_t)WELEM * sizeof(_Float16) + (size_t)NSLOT * sizeof(int4)
                      + NB * sizeof(int) + 4 * sizeof(int);
    if (ws_size >= need) {
        _Float16* wh = (_Float16*)d_ws;
        int4* dsc = (int4*)(wh + WELEM);
        int* offs = (int*)(dsc + NSLOT);
        int* nblk = offs + NB;
        prep_kernel<<<65, 256, 0, stream>>>(ag, offs, win, wo, wh, dsc, nblk);
        fused_attn_kernel<<<NB, 256, 0, stream>>>(x, wh, bin, wh + 49152, bo, dsc, nblk, out);
    } else {
        int* offs = (int*)d_ws;
        prep_kernel<<<1, 256, 0, stream>>>(ag, offs, nullptr, nullptr, nullptr, nullptr, nullptr);
        attn_fused_kernel<<<NB, 256, 0, stream>>>(x, win, bin, wo, bo, ag, offs, out);
    }
}